// Round 20
// baseline (96.224 us; speedup 1.0000x reference)
//
#include <hip/hip_runtime.h>
#include <hip/hip_bf16.h>

#define NB 16384
#define NT 32
#define NI 27
#define NH 32
#define NG 26

typedef __attribute__((ext_vector_type(8))) short bf16x8;
typedef __attribute__((ext_vector_type(4))) float f32x4;
typedef __attribute__((ext_vector_type(4))) int   i32x4;

#define MFMA(a, b, c) __builtin_amdgcn_mfma_f32_16x16x32_bf16((a), (b), (c), 0, 0, 0)
#define SWZ_XOR8 0x201F   // BitMode: xor=8, and=0x1F -> lane <-> lane^8

static __device__ __forceinline__ int pack2(float lo, float hi) {
    unsigned short a = __builtin_bit_cast(unsigned short, __float2bfloat16(lo));
    unsigned short b = __builtin_bit_cast(unsigned short, __float2bfloat16(hi));
    return (int)(((unsigned)b << 16) | (unsigned)a);
}

// A-fragment builders (verified R9-R19). perm: pi(8*g4+j)=16*(j>>2)+4*g4+(j&3).
static __device__ __forceinline__ i32x4 make_wfrag(const float* __restrict__ W,
                                                   int rowlen, int nrows, int row,
                                                   int g4, int kbase, bool perm) {
    int w[4];
#pragma unroll
    for (int q = 0; q < 4; ++q) {
        int klo = perm ? (16 * (q >> 1) + 4 * g4 + ((2 * q) & 3))
                       : (kbase + 8 * g4 + 2 * q);
        int khi = klo + 1;
        float lo = (row < nrows && klo < rowlen) ? W[row * rowlen + klo] : 0.0f;
        float hi = (row < nrows && khi < rowlen) ? W[row * rowlen + khi] : 0.0f;
        w[q] = pack2(lo, hi);
    }
    i32x4 v = { w[0], w[1], w[2], w[3] };
    return v;
}

// Wih0 with layer-0 bias folded into virtual column NI (x[NI] := 1.0).
static __device__ __forceinline__ i32x4 make_wfrag_xb(const float* __restrict__ W,
                                                      const float* __restrict__ bi,
                                                      const float* __restrict__ bh,
                                                      int row, int g4) {
    int w[4];
#pragma unroll
    for (int q = 0; q < 4; ++q) {
        int klo = 8 * g4 + 2 * q;
        int khi = klo + 1;
        float lo = (klo < NI) ? W[row * NI + klo] : ((klo == NI) ? bi[row] + bh[row] : 0.0f);
        float hi = (khi < NI) ? W[row * NI + khi] : ((khi == NI) ? bi[row] + bh[row] : 0.0f);
        w[q] = pack2(lo, hi);
    }
    i32x4 v = { w[0], w[1], w[2], w[3] };
    return v;
}

// Own-half act (hn[r] = h[16*mh+4*g4+r]) -> full pi-order B-frag via partner
// lane (lane^8) ds_swizzle. Verified R10-R13.
static __device__ __forceinline__ bf16x8 join_bfrag(const float hn[4], bool mh1) {
    int p0 = pack2(hn[0], hn[1]);
    int p1 = pack2(hn[2], hn[3]);
    int q0 = __builtin_amdgcn_ds_swizzle(p0, SWZ_XOR8);
    int q1 = __builtin_amdgcn_ds_swizzle(p1, SWZ_XOR8);
    i32x4 v = { mh1 ? q0 : p0, mh1 ? q1 : p1, mh1 ? p0 : q0, mh1 ? p1 : q1 };
    return __builtin_bit_cast(bf16x8, v);
}

// BEST CONFIGURATION (R13, 67.9 us): weights live in LDS as pre-packed
// fragments (staged once, ds_read_b128 per step) -> per-wave VGPR 120 <= 128
// -> 2 waves/SIMD (the residency boundary: <=128 regs = 2 waves, 132 = 1).
// Wave = dup2: 8 batches in 2 col-copies, activation halved per lane;
// barrier-free recurrence; pi-permuted weight columns kill the redist.
// R14-R19 all regressed: 4-wave variants hit the 64-reg wall (spill),
// dual-chain ILP costs 2x accumulators (160 regs -> 1 wave), trans-algebra
// and DPP/reorder micro-opts either serialize the chain or tip the cliff.
__global__ __launch_bounds__(256)
void lstm_lds(const float* __restrict__ X,   // [B,T,I] flat, consumed as [T,B,I]
              const float* __restrict__ Gu,  // [B,26]
              const float* __restrict__ H0, const float* __restrict__ C0,
              const float* __restrict__ Wih0, const float* __restrict__ Whh0,
              const float* __restrict__ bih0, const float* __restrict__ bhh0,
              const float* __restrict__ Wih1, const float* __restrict__ Whh1,
              const float* __restrict__ bih1, const float* __restrict__ bhh1,
              const float* __restrict__ Wfc, const float* __restrict__ bfc,
              float* __restrict__ out)
{
    __shared__ i32x4 sA0x[512], sA0h[512], sA1i[512], sA1h[512];  // [m][lane]
    __shared__ f32x4 sB1[32];    // [m][g4] layer-1 bias C-init
    __shared__ i32x4 sAfc[256];  // [part][m2][lane]

    const int tid  = threadIdx.x;
    const int lane = tid & 63;
    const int bl   = lane & 15;
    const int g4   = lane >> 4;
    const int k0   = 8 * g4;
    const int wid  = blockIdx.x * 4 + (tid >> 6);
    const int batch = wid * 8 + (bl & 7);
    const bool mh1 = (bl >> 3) != 0;

    // ---------- one-time cooperative staging ----------
#pragma unroll 1
    for (int slot = tid; slot < 512; slot += 256) {
        int m = slot >> 6, ln = slot & 63;
        int bs = ln & 15, gs = ln >> 4;
        sA0x[slot] = make_wfrag_xb(Wih0, bih0, bhh0, 16 * m + bs, gs);
        sA0h[slot] = make_wfrag(Whh0, NH, 4 * NH, 16 * m + bs, gs, 0, true);
        sA1i[slot] = make_wfrag(Wih1, NH, 4 * NH, 16 * m + bs, gs, 0, true);
        sA1h[slot] = make_wfrag(Whh1, NH, 4 * NH, 16 * m + bs, gs, 0, true);
    }
    if (tid < 32) {
        int m = tid >> 2, q4 = tid & 3;
        f32x4 b;
#pragma unroll
        for (int r = 0; r < 4; ++r) {
            int gr = 16 * m + 4 * q4 + r;
            b[r] = bih1[gr] + bhh1[gr];
        }
        sB1[tid] = b;
    }
    {
        int part = tid >> 7, m2 = (tid >> 6) & 1, ln = tid & 63;
        int bs = ln & 15, gs = ln >> 4;
        sAfc[tid] = part ? make_wfrag(Wfc, NH + NG, NG, 16 * m2 + bs, gs, NH, false)
                         : make_wfrag(Wfc, NH + NG, NG, 16 * m2 + bs, gs, 0, true);
    }
    __syncthreads();   // only barrier; recurrence below is barrier-free

    // ---------- state init (init aliases h0/c0; both col-copies identical) ----------
    const float* h0p = H0 + (size_t)batch * NH;
    const float* c0p = C0 + (size_t)batch * NH;
    i32x4 hv = { pack2(h0p[4 * g4],          h0p[4 * g4 + 1]),
                 pack2(h0p[4 * g4 + 2],      h0p[4 * g4 + 3]),
                 pack2(h0p[16 + 4 * g4],     h0p[16 + 4 * g4 + 1]),
                 pack2(h0p[16 + 4 * g4 + 2], h0p[16 + 4 * g4 + 3]) };
    bf16x8 h1f = __builtin_bit_cast(bf16x8, hv);
    bf16x8 h2f = h1f;
    float c1[4], c2[4], hsum[4];
#pragma unroll
    for (int r = 0; r < 4; ++r) {
        float c = c0p[(mh1 ? 16 : 0) + 4 * g4 + r];
        c1[r] = c; c2[r] = c; hsum[r] = 0.0f;
    }

    // x prefetch (t=0); virtual col NI carries 1.0 for the folded layer-0 bias
    float xn[8];
    {
        const float* xp = X + (size_t)batch * NI;
#pragma unroll
        for (int j = 0; j < 8; ++j) {
            int k = k0 + j;
            xn[j] = (k < NI) ? xp[k] : ((k == NI) ? 1.0f : 0.0f);
        }
    }

    const f32x4 zero4 = { 0.0f, 0.0f, 0.0f, 0.0f };

#pragma unroll 1
    for (int t = 0; t < NT; ++t) {
        int xw[4];
#pragma unroll
        for (int q = 0; q < 4; ++q) xw[q] = pack2(xn[2 * q], xn[2 * q + 1]);
        i32x4 xv = { xw[0], xw[1], xw[2], xw[3] };
        bf16x8 xf = __builtin_bit_cast(bf16x8, xv);
        if (t + 1 < NT) {
            const float* xp = X + ((size_t)(t + 1) * NB + batch) * NI;
#pragma unroll
            for (int j = 0; j < 8; ++j) {
                int k = k0 + j;
                xn[j] = (k < NI) ? xp[k] : ((k == NI) ? 1.0f : 0.0f);
            }
        }

        f32x4 g[8];
        // ---------- layer 0 (weights streamed from LDS) ----------
#pragma unroll
        for (int m = 0; m < 8; ++m)
            g[m] = MFMA(__builtin_bit_cast(bf16x8, sA0x[m * 64 + lane]), xf, zero4);
#pragma unroll
        for (int m = 0; m < 8; ++m)
            g[m] = MFMA(__builtin_bit_cast(bf16x8, sA0h[m * 64 + lane]), h1f, g[m]);
        float hn1[4];
#pragma unroll
        for (int r = 0; r < 4; ++r) {   // compile-time indices + cndmask selects (rule #20)
            float gi_ = mh1 ? g[1][r] : g[0][r];
            float gf_ = mh1 ? g[3][r] : g[2][r];
            float gg_ = mh1 ? g[5][r] : g[4][r];
            float go_ = mh1 ? g[7][r] : g[6][r];
            float ei = __expf(-gi_);
            float ef = __expf(-gf_);
            float eg = __expf(-2.0f * gg_);
            float eo = __expf(-go_);
            float ig = (1.0f - eg) * __builtin_amdgcn_rcpf(fmaf(ei, eg, ei) + eg + 1.0f);
            float fv = __builtin_amdgcn_rcpf(1.0f + ef);
            float c  = fmaf(fv, c1[r], ig);
            c1[r] = c;
            float ec = __expf(-2.0f * c);
            hn1[r] = (1.0f - ec) * __builtin_amdgcn_rcpf(fmaf(eo, ec, eo) + ec + 1.0f);
        }
        h1f = join_bfrag(hn1, mh1);

        // ---------- layer 1 ----------
#pragma unroll
        for (int m = 0; m < 8; ++m)
            g[m] = MFMA(__builtin_bit_cast(bf16x8, sA1i[m * 64 + lane]), h1f, sB1[m * 4 + g4]);
#pragma unroll
        for (int m = 0; m < 8; ++m)
            g[m] = MFMA(__builtin_bit_cast(bf16x8, sA1h[m * 64 + lane]), h2f, g[m]);
        float hn2[4];
#pragma unroll
        for (int r = 0; r < 4; ++r) {
            float gi_ = mh1 ? g[1][r] : g[0][r];
            float gf_ = mh1 ? g[3][r] : g[2][r];
            float gg_ = mh1 ? g[5][r] : g[4][r];
            float go_ = mh1 ? g[7][r] : g[6][r];
            float ei = __expf(-gi_);
            float ef = __expf(-gf_);
            float eg = __expf(-2.0f * gg_);
            float eo = __expf(-go_);
            float ig = (1.0f - eg) * __builtin_amdgcn_rcpf(fmaf(ei, eg, ei) + eg + 1.0f);
            float fv = __builtin_amdgcn_rcpf(1.0f + ef);
            float c  = fmaf(fv, c2[r], ig);
            c2[r] = c;
            float ec = __expf(-2.0f * c);
            float h  = (1.0f - ec) * __builtin_amdgcn_rcpf(fmaf(eo, ec, eo) + ec + 1.0f);
            hn2[r] = h;
            hsum[r] += h;
        }
        h2f = join_bfrag(hn2, mh1);
    }

    // ---------- fc head ----------
    float hs[4];
#pragma unroll
    for (int r = 0; r < 4; ++r) hs[r] = hsum[r] * (1.0f / NT);
    bf16x8 hsf = join_bfrag(hs, mh1);

    int gw[4];
    {
        const float* gp = Gu + (size_t)batch * NG;
#pragma unroll
        for (int q = 0; q < 4; ++q) {
            int k = k0 + 2 * q;
            float lo = (k     < NG) ? gp[k]     : 0.0f;
            float hi = (k + 1 < NG) ? gp[k + 1] : 0.0f;
            gw[q] = pack2(lo, hi);
        }
    }
    i32x4 gv_ = { gw[0], gw[1], gw[2], gw[3] };
    bf16x8 guf = __builtin_bit_cast(bf16x8, gv_);

    f32x4 L[2];
#pragma unroll
    for (int m2 = 0; m2 < 2; ++m2)
        L[m2] = MFMA(__builtin_bit_cast(bf16x8, sAfc[m2 * 64 + lane]), hsf, zero4);
#pragma unroll
    for (int m2 = 0; m2 < 2; ++m2)
        L[m2] = MFMA(__builtin_bit_cast(bf16x8, sAfc[128 + m2 * 64 + lane]), guf, L[m2]);

    if (bl < 8) {   // col-copies hold identical logits; one writer per batch
#pragma unroll
        for (int m2 = 0; m2 < 2; ++m2)
#pragma unroll
            for (int r = 0; r < 4; ++r) {
                int row = 16 * m2 + 4 * g4 + r;
                if (row < NG) {
                    float v = L[m2][r] + bfc[row];
                    out[(size_t)batch * NG + row] = v;
                    out[(size_t)NB * NG + (size_t)batch * NG + row] =
                        __builtin_amdgcn_rcpf(1.0f + __expf(-v));
                }
            }
    }
}

extern "C" void kernel_launch(void* const* d_in, const int* in_sizes, int n_in,
                              void* d_out, int out_size, void* d_ws, size_t ws_size,
                              hipStream_t stream) {
    const float* X    = (const float*)d_in[0];
    const float* Gu   = (const float*)d_in[1];
    const float* H0   = (const float*)d_in[2];
    const float* C0   = (const float*)d_in[3];
    const float* Wih0 = (const float*)d_in[4];
    const float* Whh0 = (const float*)d_in[5];
    const float* bih0 = (const float*)d_in[6];
    const float* bhh0 = (const float*)d_in[7];
    const float* Wih1 = (const float*)d_in[8];
    const float* Whh1 = (const float*)d_in[9];
    const float* bih1 = (const float*)d_in[10];
    const float* bhh1 = (const float*)d_in[11];
    const float* Wfc  = (const float*)d_in[12];
    const float* bfc  = (const float*)d_in[13];
    float* out = (float*)d_out;

    dim3 grid(NB / 8 / 4), block(256);  // 512 blocks x 4 waves = 2048 waves -> 2/SIMD
    hipLaunchKernelGGL(lstm_lds, grid, block, 0, stream,
                       X, Gu, H0, C0, Wih0, Whh0, bih0, bhh0,
                       Wih1, Whh1, bih1, bhh1, Wfc, bfc, out);
}

// Round 21
// 83.197 us; speedup vs baseline: 1.1566x; 1.1566x over previous
//
#include <hip/hip_runtime.h>
#include <hip/hip_bf16.h>

#define NB 16384
#define NT 32
#define NI 27
#define NH 32
#define NG 26

typedef __attribute__((ext_vector_type(8))) short bf16x8;
typedef __attribute__((ext_vector_type(4))) float f32x4;
typedef __attribute__((ext_vector_type(4))) int   i32x4;

#define MFMA(a, b, c) __builtin_amdgcn_mfma_f32_16x16x32_bf16((a), (b), (c), 0, 0, 0)
#define SWZ_XOR8 0x201F   // BitMode: xor=8, and=0x1F -> lane <-> lane^8

static __device__ __forceinline__ int pack2(float lo, float hi) {
    unsigned short a = __builtin_bit_cast(unsigned short, __float2bfloat16(lo));
    unsigned short b = __builtin_bit_cast(unsigned short, __float2bfloat16(hi));
    return (int)(((unsigned)b << 16) | (unsigned)a);
}

// A-fragment builders (verified R9-R20). perm: pi(8*g4+j)=16*(j>>2)+4*g4+(j&3).
static __device__ __forceinline__ i32x4 make_wfrag(const float* __restrict__ W,
                                                   int rowlen, int nrows, int row,
                                                   int g4, int kbase, bool perm) {
    int w[4];
#pragma unroll
    for (int q = 0; q < 4; ++q) {
        int klo = perm ? (16 * (q >> 1) + 4 * g4 + ((2 * q) & 3))
                       : (kbase + 8 * g4 + 2 * q);
        int khi = klo + 1;
        float lo = (row < nrows && klo < rowlen) ? W[row * rowlen + klo] : 0.0f;
        float hi = (row < nrows && khi < rowlen) ? W[row * rowlen + khi] : 0.0f;
        w[q] = pack2(lo, hi);
    }
    i32x4 v = { w[0], w[1], w[2], w[3] };
    return v;
}

// Wih0 with layer-0 bias folded into virtual column NI (x[NI] := 1.0).
static __device__ __forceinline__ i32x4 make_wfrag_xb(const float* __restrict__ W,
                                                      const float* __restrict__ bi,
                                                      const float* __restrict__ bh,
                                                      int row, int g4) {
    int w[4];
#pragma unroll
    for (int q = 0; q < 4; ++q) {
        int klo = 8 * g4 + 2 * q;
        int khi = klo + 1;
        float lo = (klo < NI) ? W[row * NI + klo] : ((klo == NI) ? bi[row] + bh[row] : 0.0f);
        float hi = (khi < NI) ? W[row * NI + khi] : ((khi == NI) ? bi[row] + bh[row] : 0.0f);
        w[q] = pack2(lo, hi);
    }
    i32x4 v = { w[0], w[1], w[2], w[3] };
    return v;
}

// Own-half act (hn[r] = h[16*mh+4*g4+r]) -> full pi-order B-frag via partner
// lane (lane^8) ds_swizzle. Verified R10-R20.
static __device__ __forceinline__ bf16x8 join_bfrag(const float hn[4], bool mh1) {
    int p0 = pack2(hn[0], hn[1]);
    int p1 = pack2(hn[2], hn[3]);
    int q0 = __builtin_amdgcn_ds_swizzle(p0, SWZ_XOR8);
    int q1 = __builtin_amdgcn_ds_swizzle(p1, SWZ_XOR8);
    i32x4 v = { mh1 ? q0 : p0, mh1 ? q1 : p1, mh1 ? p0 : q0, mh1 ? p1 : q1 };
    return __builtin_bit_cast(bf16x8, v);
}

// R13 structure (dup2 + LDS weights + barrier-free recurrence), with the
// 2-wave residency PINNED: this toolchain compiled the identical source to
// 132 regs (R20) -> 1 wave/SIMD -> 96us (vs R13's 120 regs/2 waves/67.9us).
// __launch_bounds__(256,2) caps allocation at exactly 128 (measured R10);
// the xn[4] packed prefetch (-4 regs, proven innocuous in R18) makes the
// squeeze trivial so the cap rearranges registers instead of spilling.
__global__ __launch_bounds__(256, 2)
void lstm_r21(const float* __restrict__ X,   // [B,T,I] flat, consumed as [T,B,I]
              const float* __restrict__ Gu,  // [B,26]
              const float* __restrict__ H0, const float* __restrict__ C0,
              const float* __restrict__ Wih0, const float* __restrict__ Whh0,
              const float* __restrict__ bih0, const float* __restrict__ bhh0,
              const float* __restrict__ Wih1, const float* __restrict__ Whh1,
              const float* __restrict__ bih1, const float* __restrict__ bhh1,
              const float* __restrict__ Wfc, const float* __restrict__ bfc,
              float* __restrict__ out)
{
    __shared__ i32x4 sA0x[512], sA0h[512], sA1i[512], sA1h[512];  // [m][lane]
    __shared__ f32x4 sB1[32];    // [m][g4] layer-1 bias C-init
    __shared__ i32x4 sAfc[256];  // [part][m2][lane]

    const int tid  = threadIdx.x;
    const int lane = tid & 63;
    const int bl   = lane & 15;
    const int g4   = lane >> 4;
    const int k0   = 8 * g4;
    const int wid  = blockIdx.x * 4 + (tid >> 6);
    const int batch = wid * 8 + (bl & 7);
    const bool mh1 = (bl >> 3) != 0;

    // ---------- one-time cooperative staging ----------
#pragma unroll 1
    for (int slot = tid; slot < 512; slot += 256) {
        int m = slot >> 6, ln = slot & 63;
        int bs = ln & 15, gs = ln >> 4;
        sA0x[slot] = make_wfrag_xb(Wih0, bih0, bhh0, 16 * m + bs, gs);
        sA0h[slot] = make_wfrag(Whh0, NH, 4 * NH, 16 * m + bs, gs, 0, true);
        sA1i[slot] = make_wfrag(Wih1, NH, 4 * NH, 16 * m + bs, gs, 0, true);
        sA1h[slot] = make_wfrag(Whh1, NH, 4 * NH, 16 * m + bs, gs, 0, true);
    }
    if (tid < 32) {
        int m = tid >> 2, q4 = tid & 3;
        f32x4 b;
#pragma unroll
        for (int r = 0; r < 4; ++r) {
            int gr = 16 * m + 4 * q4 + r;
            b[r] = bih1[gr] + bhh1[gr];
        }
        sB1[tid] = b;
    }
    {
        int part = tid >> 7, m2 = (tid >> 6) & 1, ln = tid & 63;
        int bs = ln & 15, gs = ln >> 4;
        sAfc[tid] = part ? make_wfrag(Wfc, NH + NG, NG, 16 * m2 + bs, gs, NH, false)
                         : make_wfrag(Wfc, NH + NG, NG, 16 * m2 + bs, gs, 0, true);
    }
    __syncthreads();   // only barrier; recurrence below is barrier-free

    // ---------- state init (init aliases h0/c0; both col-copies identical) ----------
    const float* h0p = H0 + (size_t)batch * NH;
    const float* c0p = C0 + (size_t)batch * NH;
    i32x4 hv = { pack2(h0p[4 * g4],          h0p[4 * g4 + 1]),
                 pack2(h0p[4 * g4 + 2],      h0p[4 * g4 + 3]),
                 pack2(h0p[16 + 4 * g4],     h0p[16 + 4 * g4 + 1]),
                 pack2(h0p[16 + 4 * g4 + 2], h0p[16 + 4 * g4 + 3]) };
    bf16x8 h1f = __builtin_bit_cast(bf16x8, hv);
    bf16x8 h2f = h1f;
    float c1[4], c2[4], hsum[4];
#pragma unroll
    for (int r = 0; r < 4; ++r) {
        float c = c0p[(mh1 ? 16 : 0) + 4 * g4 + r];
        c1[r] = c; c2[r] = c; hsum[r] = 0.0f;
    }

    // x prefetch (t=0), packed at load (reg trim, R18-proven); virtual col NI = 1.0
    int xn[4];
    {
        const float* xp = X + (size_t)batch * NI;
#pragma unroll
        for (int q = 0; q < 4; ++q) {
            int klo = k0 + 2 * q, khi = klo + 1;
            float lo = (klo < NI) ? xp[klo] : ((klo == NI) ? 1.0f : 0.0f);
            float hi = (khi < NI) ? xp[khi] : ((khi == NI) ? 1.0f : 0.0f);
            xn[q] = pack2(lo, hi);
        }
    }

    const f32x4 zero4 = { 0.0f, 0.0f, 0.0f, 0.0f };

#pragma unroll 1
    for (int t = 0; t < NT; ++t) {
        i32x4 xv = { xn[0], xn[1], xn[2], xn[3] };
        bf16x8 xf = __builtin_bit_cast(bf16x8, xv);
        if (t + 1 < NT) {
            const float* xp = X + ((size_t)(t + 1) * NB + batch) * NI;
#pragma unroll
            for (int q = 0; q < 4; ++q) {
                int klo = k0 + 2 * q, khi = klo + 1;
                float lo = (klo < NI) ? xp[klo] : ((klo == NI) ? 1.0f : 0.0f);
                float hi = (khi < NI) ? xp[khi] : ((khi == NI) ? 1.0f : 0.0f);
                xn[q] = pack2(lo, hi);
            }
        }

        f32x4 g[8];
        // ---------- layer 0 (weights streamed from LDS) ----------
#pragma unroll
        for (int m = 0; m < 8; ++m)
            g[m] = MFMA(__builtin_bit_cast(bf16x8, sA0x[m * 64 + lane]), xf, zero4);
#pragma unroll
        for (int m = 0; m < 8; ++m)
            g[m] = MFMA(__builtin_bit_cast(bf16x8, sA0h[m * 64 + lane]), h1f, g[m]);
        float hn1[4];
#pragma unroll
        for (int r = 0; r < 4; ++r) {   // R13's proven act algebra (parallel rcps)
            float gi_ = mh1 ? g[1][r] : g[0][r];
            float gf_ = mh1 ? g[3][r] : g[2][r];
            float gg_ = mh1 ? g[5][r] : g[4][r];
            float go_ = mh1 ? g[7][r] : g[6][r];
            float ei = __expf(-gi_);
            float ef = __expf(-gf_);
            float eg = __expf(-2.0f * gg_);
            float eo = __expf(-go_);
            float ig = (1.0f - eg) * __builtin_amdgcn_rcpf(fmaf(ei, eg, ei) + eg + 1.0f);
            float fv = __builtin_amdgcn_rcpf(1.0f + ef);
            float c  = fmaf(fv, c1[r], ig);
            c1[r] = c;
            float ec = __expf(-2.0f * c);
            hn1[r] = (1.0f - ec) * __builtin_amdgcn_rcpf(fmaf(eo, ec, eo) + ec + 1.0f);
        }
        h1f = join_bfrag(hn1, mh1);

        // ---------- layer 1 ----------
#pragma unroll
        for (int m = 0; m < 8; ++m)
            g[m] = MFMA(__builtin_bit_cast(bf16x8, sA1i[m * 64 + lane]), h1f, sB1[m * 4 + g4]);
#pragma unroll
        for (int m = 0; m < 8; ++m)
            g[m] = MFMA(__builtin_bit_cast(bf16x8, sA1h[m * 64 + lane]), h2f, g[m]);
        float hn2[4];
#pragma unroll
        for (int r = 0; r < 4; ++r) {
            float gi_ = mh1 ? g[1][r] : g[0][r];
            float gf_ = mh1 ? g[3][r] : g[2][r];
            float gg_ = mh1 ? g[5][r] : g[4][r];
            float go_ = mh1 ? g[7][r] : g[6][r];
            float ei = __expf(-gi_);
            float ef = __expf(-gf_);
            float eg = __expf(-2.0f * gg_);
            float eo = __expf(-go_);
            float ig = (1.0f - eg) * __builtin_amdgcn_rcpf(fmaf(ei, eg, ei) + eg + 1.0f);
            float fv = __builtin_amdgcn_rcpf(1.0f + ef);
            float c  = fmaf(fv, c2[r], ig);
            c2[r] = c;
            float ec = __expf(-2.0f * c);
            float h  = (1.0f - ec) * __builtin_amdgcn_rcpf(fmaf(eo, ec, eo) + ec + 1.0f);
            hn2[r] = h;
            hsum[r] += h;
        }
        h2f = join_bfrag(hn2, mh1);
    }

    // ---------- fc head ----------
    float hs[4];
#pragma unroll
    for (int r = 0; r < 4; ++r) hs[r] = hsum[r] * (1.0f / NT);
    bf16x8 hsf = join_bfrag(hs, mh1);

    int gw[4];
    {
        const float* gp = Gu + (size_t)batch * NG;
#pragma unroll
        for (int q = 0; q < 4; ++q) {
            int k = k0 + 2 * q;
            float lo = (k     < NG) ? gp[k]     : 0.0f;
            float hi = (k + 1 < NG) ? gp[k + 1] : 0.0f;
            gw[q] = pack2(lo, hi);
        }
    }
    i32x4 gv_ = { gw[0], gw[1], gw[2], gw[3] };
    bf16x8 guf = __builtin_bit_cast(bf16x8, gv_);

    f32x4 L[2];
#pragma unroll
    for (int m2 = 0; m2 < 2; ++m2)
        L[m2] = MFMA(__builtin_bit_cast(bf16x8, sAfc[m2 * 64 + lane]), hsf, zero4);
#pragma unroll
    for (int m2 = 0; m2 < 2; ++m2)
        L[m2] = MFMA(__builtin_bit_cast(bf16x8, sAfc[128 + m2 * 64 + lane]), guf, L[m2]);

    if (bl < 8) {   // col-copies hold identical logits; one writer per batch
#pragma unroll
        for (int m2 = 0; m2 < 2; ++m2)
#pragma unroll
            for (int r = 0; r < 4; ++r) {
                int row = 16 * m2 + 4 * g4 + r;
                if (row < NG) {
                    float v = L[m2][r] + bfc[row];
                    out[(size_t)batch * NG + row] = v;
                    out[(size_t)NB * NG + (size_t)batch * NG + row] =
                        __builtin_amdgcn_rcpf(1.0f + __expf(-v));
                }
            }
    }
}

extern "C" void kernel_launch(void* const* d_in, const int* in_sizes, int n_in,
                              void* d_out, int out_size, void* d_ws, size_t ws_size,
                              hipStream_t stream) {
    const float* X    = (const float*)d_in[0];
    const float* Gu   = (const float*)d_in[1];
    const float* H0   = (const float*)d_in[2];
    const float* C0   = (const float*)d_in[3];
    const float* Wih0 = (const float*)d_in[4];
    const float* Whh0 = (const float*)d_in[5];
    const float* bih0 = (const float*)d_in[6];
    const float* bhh0 = (const float*)d_in[7];
    const float* Wih1 = (const float*)d_in[8];
    const float* Whh1 = (const float*)d_in[9];
    const float* bih1 = (const float*)d_in[10];
    const float* bhh1 = (const float*)d_in[11];
    const float* Wfc  = (const float*)d_in[12];
    const float* bfc  = (const float*)d_in[13];
    float* out = (float*)d_out;

    dim3 grid(NB / 8 / 4), block(256);  // 512 blocks x 4 waves = 2048 waves -> 2/SIMD
    hipLaunchKernelGGL(lstm_r21, grid, block, 0, stream,
                       X, Gu, H0, C0, Wih0, Whh0, bih0, bhh0,
                       Wih1, Whh1, bih1, bhh1, Wfc, bfc, out);
}